// Round 3
// baseline (186.785 us; speedup 1.0000x reference)
//
#include <hip/hip_runtime.h>
#include <hip/hip_bf16.h>

typedef __attribute__((ext_vector_type(8))) short sh8;        // 8 x bf16 bits (4 VGPR)
typedef __attribute__((ext_vector_type(16))) float fx16;      // MFMA 32x32 accumulator
typedef __attribute__((ext_vector_type(4))) unsigned int u32x4;

__device__ __forceinline__ unsigned short f2bits(float a) {
  union { __hip_bfloat16 h; unsigned short u; } c;
  c.h = __float2bfloat16(a);
  return c.u;
}
__device__ __forceinline__ unsigned int pk2(float a, float b) {
  return (unsigned int)f2bits(a) | ((unsigned int)f2bits(b) << 16);
}
__device__ __forceinline__ fx16 fzero16() {
  fx16 z;
  #pragma unroll
  for (int i = 0; i < 16; ++i) z[i] = 0.0f;
  return z;
}

// v_permlane32_swap_b32 a, b:
//   post: a = {a.lo, b.lo}, b = {a.hi_old, b.hi}
#define SWAP32(a, b) asm volatile("v_permlane32_swap_b32 %0, %1" : "+v"(a), "+v"(b))

// ---------------------------------------------------------------------------
// Kernel 1: batched Cayley transform Q = (I-A)(I+A)^-1 for P1 (64) and P2 (64).
// ---------------------------------------------------------------------------
__global__ void k_cayley(const float* __restrict__ P1, const float* __restrict__ P2,
                         float* __restrict__ Qout) {
  int t = blockIdx.x * blockDim.x + threadIdx.x;
  int mat = t >> 4;
  int row = t & 15;
  if (mat >= 128) return;
  const float* P = (mat < 64) ? (P1 + mat * 256) : (P2 + (mat - 64) * 256);
  float M[16], Rr[16];
  #pragma unroll
  for (int j = 0; j < 16; ++j) {
    float a = 0.0f;
    if (j > row) a = P[row * 16 + j];
    if (j < row) a = -P[j * 16 + row];
    float d = (j == row) ? 1.0f : 0.0f;
    M[j]  = d + a;
    Rr[j] = d - a;
  }
  int gbase = (threadIdx.x & 63) & ~15;
  #pragma unroll
  for (int k = 0; k < 16; ++k) {
    float pkk = __shfl(M[k], gbase + k);
    float inv = 1.0f / pkk;
    float pM[16], pR[16];
    #pragma unroll
    for (int j = 0; j < 16; ++j) {
      pM[j] = __shfl(M[j], gbase + k) * inv;
      pR[j] = __shfl(Rr[j], gbase + k) * inv;
    }
    if (row == k) {
      #pragma unroll
      for (int j = 0; j < 16; ++j) { M[j] = pM[j]; Rr[j] = pR[j]; }
    } else {
      float f = M[k];
      #pragma unroll
      for (int j = 0; j < 16; ++j) { M[j] -= f * pM[j]; Rr[j] -= f * pR[j]; }
    }
  }
  float* qo = Qout + mat * 256 + row * 16;
  #pragma unroll
  for (int j = 0; j < 16; ++j) qo[j] = Rr[j];
}

// ---------------------------------------------------------------------------
// Kernel 2: build folded weights in bf16, MFMA B-fragment order (see R1 notes).
// W[t2][tile(2)][kstep(4)][lane(64)][r(8)] bf16;
// element = B[k = kstep*16 + (lane>>5)*8 + r, n = tile*32 + (lane&31)].
// ---------------------------------------------------------------------------
__global__ void k_build(const float* __restrict__ P0, const float* __restrict__ P3,
                        const float* __restrict__ Qbuf,
                        unsigned short* __restrict__ W1, unsigned short* __restrict__ W2) {
  int t = blockIdx.x * blockDim.x + threadIdx.x;
  if (t >= 131072) return;
  const float* Q1 = Qbuf;
  const float* Q2 = Qbuf + 16384;
  int e  = t & 65535;
  int r  = e & 7;
  int l  = (e >> 3) & 63;
  int kx = (e >> 9) & 3;
  int mt = (e >> 11) & 1;
  int t2 = (e >> 12) & 15;
  int h8 = ((l >> 5) << 3);
  float acc = 0.0f;
  if (t < 65536) {
    int m = mt * 32 + (l & 31);
    int q = kx * 16 + h8 + r;
    int j0 = m >> 3, j1 = m & 7, i0 = q >> 3, i1 = q & 7;
    #pragma unroll
    for (int t1 = 0; t1 < 16; ++t1) {
      float c0 = P0[(j0 * 8 + (t1 >> 1)) * 16 + ((t1 & 1) * 8 + i0)];
      int a1 = j1 * 16 + t2, u1 = t1 * 8 + i1;
      float c1 = Q1[((a1 & 7) * 8 + (u1 >> 4)) * 256 + (a1 >> 3) * 16 + (u1 & 15)];
      acc += c0 * c1;
    }
    W1[e] = f2bits(acc);
  } else {
    int n = mt * 32 + (l & 31);
    int s = kx * 16 + h8 + r;
    int j2 = n >> 3, j3 = n & 7, i2 = s >> 3, i3 = s & 7;
    #pragma unroll
    for (int t3 = 0; t3 < 16; ++t3) {
      int a2 = j2 * 16 + t3, u2 = t2 * 8 + i2;
      float c2 = Q2[((a2 & 7) * 8 + (u2 >> 4)) * 256 + (a2 >> 3) * 16 + (u2 & 15)];
      float c3 = P3[((t3 & 7) * 8 + i3) * 16 + (j3 * 2 + (t3 >> 3))];
      acc += c2 * c3;
    }
    W2[e] = f2bits(acc);
  }
}

// ---------------------------------------------------------------------------
// Kernel 3: fused main. Wave-pair per batch element: wave w handles m-half
// mh = w&1 of out_b. Per t2: GEMM1 (8 MFMA) Y^T[s,mh], in-register pack
// (cvt_pk + permlane32_swap), GEMM2 (8 MFMA) out[mh,:] += Y @ B23_t2.
// 3 waves/SIMD target via __launch_bounds__(256,3); wave-staggered t2 order;
// zero-init via hoisted zero C-operand; weights from L2; one barrier total.
// ---------------------------------------------------------------------------
__global__ __launch_bounds__(256, 3) void k_main(
    const float* __restrict__ x,
    const unsigned short* __restrict__ W1,
    const unsigned short* __restrict__ W2,
    const float* __restrict__ bias,
    float* __restrict__ out) {
  __shared__ __align__(16) char XsT[2 * 8192];   // [elem][64 rows s][128 B], swizzled

  const int tid  = threadIdx.x;
  const int lane = tid & 63;
  const int w    = tid >> 6;
  const int h    = lane >> 5;
  const int l31  = lane & 31;
  const int elem = w >> 1;        // 0,1
  const int mh   = w & 1;         // m-half this wave owns
  const size_t b = (size_t)blockIdx.x * 2 + elem;

  // ---- Cooperative stage of both X elems (f32 -> bf16, [s][q] swizzled) ----
  {
    int e  = tid >> 7;            // elem staged by this thread
    int s  = tid & 63;
    int qh = (tid >> 6) & 1;      // q-half
    const float* xb = x + ((size_t)blockIdx.x * 2 + e) * 4096;
    const unsigned sw = ((unsigned)(s & 7)) << 4;
    char* base = XsT + e * 8192 + s * 128;
    #pragma unroll
    for (int c = 0; c < 2; ++c) {               // 16 q per chunk
      int qb = qh * 32 + c * 16;
      unsigned int d[8];
      #pragma unroll
      for (int jj = 0; jj < 8; ++jj) {
        float a  = xb[(qb + 2 * jj + 0) * 64 + s];
        float bq = xb[(qb + 2 * jj + 1) * 64 + s];
        d[jj] = pk2(a, bq);
      }
      u32x4 v0 = {d[0], d[1], d[2], d[3]};
      u32x4 v1 = {d[4], d[5], d[6], d[7]};
      *(u32x4*)(base + (((unsigned)(qb * 2)) ^ sw))      = v0;
      *(u32x4*)(base + (((unsigned)(qb * 2 + 16)) ^ sw)) = v1;
    }
  }
  __syncthreads();

  // ---- Hoist GEMM1 A-frags (loop-invariant): 8 x ds_read_b128 ----
  const char* myX = XsT + elem * 8192;
  sh8 af[2][4];
  #pragma unroll
  for (int st = 0; st < 2; ++st)
    #pragma unroll
    for (int kq = 0; kq < 4; ++kq) {
      int srow = st * 32 + l31;
      unsigned boff = (unsigned)srow * 128 +
                      (((unsigned)(kq * 32 + h * 16)) ^ (((unsigned)(srow & 7)) << 4));
      af[st][kq] = *(const sh8*)(myX + boff);
    }

  const fx16 zc = fzero16();      // hoisted zero C-operand
  fx16 accO[2];
  accO[0] = zc; accO[1] = zc;

  const sh8* w1f = (const sh8*)W1;   // idx: t2*512 + (tile*4+kstep)*64 + lane
  const sh8* w2f = (const sh8*)W2;

  #pragma unroll 2
  for (int it = 0; it < 16; ++it) {
    const int t2 = (it + w * 4) & 15;    // wave-staggered phase (sum is t2-order-free)

    // ---- GEMM1: Y^T(s, mh-half) = X_b^T @ B01_t2^T  (8 MFMA) ----
    sh8 b1[4];
    #pragma unroll
    for (int kq = 0; kq < 4; ++kq)
      b1[kq] = w1f[t2 * 512 + (mh * 4 + kq) * 64 + lane];

    fx16 accY[2];
    __builtin_amdgcn_s_setprio(1);
    #pragma unroll
    for (int st = 0; st < 2; ++st) {
      accY[st] = __builtin_amdgcn_mfma_f32_32x32x16_bf16(af[st][0], b1[0], zc, 0, 0, 0);
      #pragma unroll
      for (int kq = 1; kq < 4; ++kq)
        accY[st] = __builtin_amdgcn_mfma_f32_32x32x16_bf16(af[st][kq], b1[kq], accY[st], 0, 0, 0);
    }
    __builtin_amdgcn_s_setprio(0);

    // ---- pack Y^T C/D (col=m=lane&31, row=s=(reg&3)+8*(reg>>2)+4*h) -> A-frags
    sh8 ga[4];
    #pragma unroll
    for (int st = 0; st < 2; ++st) {
      fx16 Y = accY[st];
      unsigned int P0 = pk2(Y[0],  Y[1]),  P1 = pk2(Y[2],  Y[3]);
      unsigned int P2 = pk2(Y[4],  Y[5]),  P3 = pk2(Y[6],  Y[7]);
      unsigned int P4 = pk2(Y[8],  Y[9]),  P5 = pk2(Y[10], Y[11]);
      unsigned int P6 = pk2(Y[12], Y[13]), P7 = pk2(Y[14], Y[15]);
      SWAP32(P0, P2); SWAP32(P1, P3);
      SWAP32(P4, P6); SWAP32(P5, P7);
      union { u32x4 u; sh8 s8; } c0, c1;
      c0.u = (u32x4){P0, P1, P2, P3};
      c1.u = (u32x4){P4, P5, P6, P7};
      ga[st * 2 + 0] = c0.s8;
      ga[st * 2 + 1] = c1.s8;
    }

    // ---- GEMM2: out[mh,:] += Y @ B23_t2  (8 MFMA) ----
    __builtin_amdgcn_s_setprio(1);
    #pragma unroll
    for (int nt = 0; nt < 2; ++nt) {
      #pragma unroll
      for (int ks = 0; ks < 4; ++ks) {
        sh8 b2 = w2f[t2 * 512 + (nt * 4 + ks) * 64 + lane];
        accO[nt] = __builtin_amdgcn_mfma_f32_32x32x16_bf16(ga[ks], b2, accO[nt], 0, 0, 0);
      }
    }
    __builtin_amdgcn_s_setprio(0);
  }

  // ---- epilogue: out[b][m*64+n] = acc + bias ----
  float* ob = out + b * 4096;
  #pragma unroll
  for (int nt = 0; nt < 2; ++nt) {
    #pragma unroll
    for (int reg = 0; reg < 16; ++reg) {
      int m = mh * 32 + (reg & 3) + 8 * (reg >> 2) + 4 * h;
      int n = nt * 32 + l31;
      int o = m * 64 + n;
      ob[o] = accO[nt][reg] + bias[o];
    }
  }
}

// ---------------------------------------------------------------------------
extern "C" void kernel_launch(void* const* d_in, const int* in_sizes, int n_in,
                              void* d_out, int out_size, void* d_ws, size_t ws_size,
                              hipStream_t stream) {
  (void)n_in; (void)out_size; (void)ws_size;
  const float* x    = (const float*)d_in[0];
  const float* P0   = (const float*)d_in[1];
  const float* P1   = (const float*)d_in[2];
  const float* P2   = (const float*)d_in[3];
  const float* P3   = (const float*)d_in[4];
  const float* bias = (const float*)d_in[5];
  float* out = (float*)d_out;

  // ws: Qbuf f32[128*256] (128 KB) | W1 bf16[65536] (128 KB) | W2 bf16[65536] (128 KB)
  float* Qbuf = (float*)d_ws;
  unsigned short* W1 = (unsigned short*)((char*)d_ws + 131072);
  unsigned short* W2 = (unsigned short*)((char*)d_ws + 262144);

  k_cayley<<<8, 256, 0, stream>>>(P1, P2, Qbuf);
  k_build<<<512, 256, 0, stream>>>(P0, P3, Qbuf, W1, W2);

  int batch = in_sizes[0] / 4096;
  k_main<<<batch / 2, 256, 0, stream>>>(x, W1, W2, bias, out);
}

// Round 4
// 160.542 us; speedup vs baseline: 1.1635x; 1.1635x over previous
//
#include <hip/hip_runtime.h>
#include <hip/hip_bf16.h>

typedef __attribute__((ext_vector_type(8))) short sh8;        // 8 x bf16 bits (4 VGPR)
typedef __attribute__((ext_vector_type(16))) float fx16;      // MFMA 32x32 accumulator
typedef __attribute__((ext_vector_type(4))) unsigned int u32x4;

__device__ __forceinline__ unsigned short f2bits(float a) {
  union { __hip_bfloat16 h; unsigned short u; } c;
  c.h = __float2bfloat16(a);
  return c.u;
}
__device__ __forceinline__ unsigned int pk2(float a, float b) {
  return (unsigned int)f2bits(a) | ((unsigned int)f2bits(b) << 16);
}
__device__ __forceinline__ fx16 fzero16() {
  fx16 z;
  #pragma unroll
  for (int i = 0; i < 16; ++i) z[i] = 0.0f;
  return z;
}

// v_permlane32_swap_b32 a, b:  post: a = {a.lo, b.lo}, b = {a.hi_old, b.hi}
#define SWAP32(a, b) asm volatile("v_permlane32_swap_b32 %0, %1" : "+v"(a), "+v"(b))

// ---------------------------------------------------------------------------
// Kernel 1: batched Cayley transform Q = (I-A)(I+A)^-1 for P1 (64) and P2 (64).
// ---------------------------------------------------------------------------
__global__ void k_cayley(const float* __restrict__ P1, const float* __restrict__ P2,
                         float* __restrict__ Qout) {
  int t = blockIdx.x * blockDim.x + threadIdx.x;
  int mat = t >> 4;
  int row = t & 15;
  if (mat >= 128) return;
  const float* P = (mat < 64) ? (P1 + mat * 256) : (P2 + (mat - 64) * 256);
  float M[16], Rr[16];
  #pragma unroll
  for (int j = 0; j < 16; ++j) {
    float a = 0.0f;
    if (j > row) a = P[row * 16 + j];
    if (j < row) a = -P[j * 16 + row];
    float d = (j == row) ? 1.0f : 0.0f;
    M[j]  = d + a;
    Rr[j] = d - a;
  }
  int gbase = (threadIdx.x & 63) & ~15;
  #pragma unroll
  for (int k = 0; k < 16; ++k) {
    float pkk = __shfl(M[k], gbase + k);
    float inv = 1.0f / pkk;
    float pM[16], pR[16];
    #pragma unroll
    for (int j = 0; j < 16; ++j) {
      pM[j] = __shfl(M[j], gbase + k) * inv;
      pR[j] = __shfl(Rr[j], gbase + k) * inv;
    }
    if (row == k) {
      #pragma unroll
      for (int j = 0; j < 16; ++j) { M[j] = pM[j]; Rr[j] = pR[j]; }
    } else {
      float f = M[k];
      #pragma unroll
      for (int j = 0; j < 16; ++j) { M[j] -= f * pM[j]; Rr[j] -= f * pR[j]; }
    }
  }
  float* qo = Qout + mat * 256 + row * 16;
  #pragma unroll
  for (int j = 0; j < 16; ++j) qo[j] = Rr[j];
}

// ---------------------------------------------------------------------------
// Kernel 2: build folded weights in bf16, MFMA B-fragment order.
// W[t2][tile(2)][kstep(4)][lane(64)][r(8)] bf16;
// element = B[k = kstep*16 + (lane>>5)*8 + r, n = tile*32 + (lane&31)].
// ---------------------------------------------------------------------------
__global__ void k_build(const float* __restrict__ P0, const float* __restrict__ P3,
                        const float* __restrict__ Qbuf,
                        unsigned short* __restrict__ W1, unsigned short* __restrict__ W2) {
  int t = blockIdx.x * blockDim.x + threadIdx.x;
  if (t >= 131072) return;
  const float* Q1 = Qbuf;
  const float* Q2 = Qbuf + 16384;
  int e  = t & 65535;
  int r  = e & 7;
  int l  = (e >> 3) & 63;
  int kx = (e >> 9) & 3;
  int mt = (e >> 11) & 1;
  int t2 = (e >> 12) & 15;
  int h8 = ((l >> 5) << 3);
  float acc = 0.0f;
  if (t < 65536) {
    int m = mt * 32 + (l & 31);
    int q = kx * 16 + h8 + r;
    int j0 = m >> 3, j1 = m & 7, i0 = q >> 3, i1 = q & 7;
    #pragma unroll
    for (int t1 = 0; t1 < 16; ++t1) {
      float c0 = P0[(j0 * 8 + (t1 >> 1)) * 16 + ((t1 & 1) * 8 + i0)];
      int a1 = j1 * 16 + t2, u1 = t1 * 8 + i1;
      float c1 = Q1[((a1 & 7) * 8 + (u1 >> 4)) * 256 + (a1 >> 3) * 16 + (u1 & 15)];
      acc += c0 * c1;
    }
    W1[e] = f2bits(acc);
  } else {
    int n = mt * 32 + (l & 31);
    int s = kx * 16 + h8 + r;
    int j2 = n >> 3, j3 = n & 7, i2 = s >> 3, i3 = s & 7;
    #pragma unroll
    for (int t3 = 0; t3 < 16; ++t3) {
      int a2 = j2 * 16 + t3, u2 = t2 * 8 + i2;
      float c2 = Q2[((a2 & 7) * 8 + (u2 >> 4)) * 256 + (a2 >> 3) * 16 + (u2 & 15)];
      float c3 = P3[((t3 & 7) * 8 + i3) * 16 + (j3 * 2 + (t3 >> 3))];
      acc += c2 * c3;
    }
    W2[e] = f2bits(acc);
  }
}

// ---------------------------------------------------------------------------
// Kernel 3: fused main. WG = 4 waves / 4 batch elems. Wave w: elem pair
// ep = (w>>1)*2 .. +1, m-half mh = w&1. Per t2 iteration the wave does
// 32 MFMA across 2 elems sharing ONE set of weight fragments (b1:4, b2:8),
// ordered so each element's pack/chain latency hides under the other
// element's independent MFMA stream. Weights stream from L2 (256 KB total,
// same t2 for all waves -> <=16 KB L1 working set). 2 waves/SIMD by design.
// ---------------------------------------------------------------------------
__global__ __launch_bounds__(256, 2) void k_main(
    const float* __restrict__ x,
    const unsigned short* __restrict__ W1,
    const unsigned short* __restrict__ W2,
    const float* __restrict__ bias,
    float* __restrict__ out) {
  __shared__ __align__(16) char XsT[4 * 8192];   // [elem][64 s][128 B], swizzled

  const int tid  = threadIdx.x;
  const int lane = tid & 63;
  const int w    = tid >> 6;
  const int h    = lane >> 5;
  const int l31  = lane & 31;
  const int ep   = (w >> 1) * 2;   // first elem of this wave's pair
  const int mh   = w & 1;          // m-half this wave owns
  const size_t bbase = (size_t)blockIdx.x * 4;

  // ---- Wave w stages elem w (f32 -> bf16, [s][q] transposed, swizzled) ----
  {
    const int s = lane;
    const float* xb = x + (bbase + w) * 4096;
    const unsigned sw = ((unsigned)(s & 7)) << 4;
    char* base = XsT + w * 8192 + s * 128;
    #pragma unroll
    for (int c = 0; c < 4; ++c) {               // 16 q per chunk
      unsigned int d[8];
      #pragma unroll
      for (int jj = 0; jj < 8; ++jj) {
        float a  = xb[(c * 16 + 2 * jj + 0) * 64 + s];
        float bq = xb[(c * 16 + 2 * jj + 1) * 64 + s];
        d[jj] = pk2(a, bq);
      }
      u32x4 v0 = {d[0], d[1], d[2], d[3]};
      u32x4 v1 = {d[4], d[5], d[6], d[7]};
      *(u32x4*)(base + (((unsigned)(c * 32)) ^ sw))      = v0;
      *(u32x4*)(base + (((unsigned)(c * 32 + 16)) ^ sw)) = v1;
    }
  }
  __syncthreads();

  // ---- Hoist GEMM1 A-frags for both elems (loop-invariant): 16 ds_read_b128
  sh8 af[2][2][4];
  #pragma unroll
  for (int e = 0; e < 2; ++e) {
    const char* myX = XsT + (ep + e) * 8192;
    #pragma unroll
    for (int st = 0; st < 2; ++st)
      #pragma unroll
      for (int kq = 0; kq < 4; ++kq) {
        int srow = st * 32 + l31;
        unsigned boff = (unsigned)srow * 128 +
                        (((unsigned)(kq * 32 + h * 16)) ^ (((unsigned)(srow & 7)) << 4));
        af[e][st][kq] = *(const sh8*)(myX + boff);
      }
  }

  const fx16 zc = fzero16();
  fx16 accO[2][2];                 // [elem][nt]
  accO[0][0] = zc; accO[0][1] = zc;
  accO[1][0] = zc; accO[1][1] = zc;

  const sh8* w1f = (const sh8*)W1;   // idx: t2*512 + (tile*4+kstep)*64 + lane
  const sh8* w2f = (const sh8*)W2;

  for (int t2 = 0; t2 < 16; ++t2) {
    // ---- weight frags for this t2, shared by both elems (12 VMEM @ top) ----
    sh8 b1[4];
    #pragma unroll
    for (int kq = 0; kq < 4; ++kq)
      b1[kq] = w1f[t2 * 512 + (mh * 4 + kq) * 64 + lane];
    sh8 b2[2][4];
    #pragma unroll
    for (int nt = 0; nt < 2; ++nt)
      #pragma unroll
      for (int ks = 0; ks < 4; ++ks)
        b2[nt][ks] = w2f[t2 * 512 + (nt * 4 + ks) * 64 + lane];

    // ---- GEMM1 elem0 ----
    fx16 accY[2];
    __builtin_amdgcn_s_setprio(1);
    #pragma unroll
    for (int st = 0; st < 2; ++st) {
      accY[st] = __builtin_amdgcn_mfma_f32_32x32x16_bf16(af[0][st][0], b1[0], zc, 0, 0, 0);
      #pragma unroll
      for (int kq = 1; kq < 4; ++kq)
        accY[st] = __builtin_amdgcn_mfma_f32_32x32x16_bf16(af[0][st][kq], b1[kq], accY[st], 0, 0, 0);
    }
    __builtin_amdgcn_s_setprio(0);

    // ---- pack elem0: C/D (col=m, row=s) -> GEMM2 A-frags ga0 ----
    sh8 ga0[4];
    #pragma unroll
    for (int st = 0; st < 2; ++st) {
      fx16 Y = accY[st];
      unsigned int P0 = pk2(Y[0],  Y[1]),  P1 = pk2(Y[2],  Y[3]);
      unsigned int P2 = pk2(Y[4],  Y[5]),  P3 = pk2(Y[6],  Y[7]);
      unsigned int P4 = pk2(Y[8],  Y[9]),  P5 = pk2(Y[10], Y[11]);
      unsigned int P6 = pk2(Y[12], Y[13]), P7 = pk2(Y[14], Y[15]);
      SWAP32(P0, P2); SWAP32(P1, P3);
      SWAP32(P4, P6); SWAP32(P5, P7);
      union { u32x4 u; sh8 s8; } c0, c1;
      c0.u = (u32x4){P0, P1, P2, P3};
      c1.u = (u32x4){P4, P5, P6, P7};
      ga0[st * 2 + 0] = c0.s8;
      ga0[st * 2 + 1] = c1.s8;
    }

    // ---- GEMM1 elem1 (independent MFMA stream; reuses accY) ----
    fx16 accZ[2];
    __builtin_amdgcn_s_setprio(1);
    #pragma unroll
    for (int st = 0; st < 2; ++st) {
      accZ[st] = __builtin_amdgcn_mfma_f32_32x32x16_bf16(af[1][st][0], b1[0], zc, 0, 0, 0);
      #pragma unroll
      for (int kq = 1; kq < 4; ++kq)
        accZ[st] = __builtin_amdgcn_mfma_f32_32x32x16_bf16(af[1][st][kq], b1[kq], accZ[st], 0, 0, 0);
    }

    // ---- GEMM2 elem0 (hides elem1's chain drain) ----
    #pragma unroll
    for (int nt = 0; nt < 2; ++nt)
      #pragma unroll
      for (int ks = 0; ks < 4; ++ks)
        accO[0][nt] = __builtin_amdgcn_mfma_f32_32x32x16_bf16(ga0[ks], b2[nt][ks], accO[0][nt], 0, 0, 0);
    __builtin_amdgcn_s_setprio(0);

    // ---- pack elem1 (during GEMM2-e0 drain) ----
    sh8 ga1[4];
    #pragma unroll
    for (int st = 0; st < 2; ++st) {
      fx16 Y = accZ[st];
      unsigned int P0 = pk2(Y[0],  Y[1]),  P1 = pk2(Y[2],  Y[3]);
      unsigned int P2 = pk2(Y[4],  Y[5]),  P3 = pk2(Y[6],  Y[7]);
      unsigned int P4 = pk2(Y[8],  Y[9]),  P5 = pk2(Y[10], Y[11]);
      unsigned int P6 = pk2(Y[12], Y[13]), P7 = pk2(Y[14], Y[15]);
      SWAP32(P0, P2); SWAP32(P1, P3);
      SWAP32(P4, P6); SWAP32(P5, P7);
      union { u32x4 u; sh8 s8; } c0, c1;
      c0.u = (u32x4){P0, P1, P2, P3};
      c1.u = (u32x4){P4, P5, P6, P7};
      ga1[st * 2 + 0] = c0.s8;
      ga1[st * 2 + 1] = c1.s8;
    }

    // ---- GEMM2 elem1 ----
    __builtin_amdgcn_s_setprio(1);
    #pragma unroll
    for (int nt = 0; nt < 2; ++nt)
      #pragma unroll
      for (int ks = 0; ks < 4; ++ks)
        accO[1][nt] = __builtin_amdgcn_mfma_f32_32x32x16_bf16(ga1[ks], b2[nt][ks], accO[1][nt], 0, 0, 0);
    __builtin_amdgcn_s_setprio(0);
  }

  // ---- epilogue ----
  #pragma unroll
  for (int e = 0; e < 2; ++e) {
    float* ob = out + (bbase + ep + e) * 4096;
    #pragma unroll
    for (int nt = 0; nt < 2; ++nt) {
      #pragma unroll
      for (int reg = 0; reg < 16; ++reg) {
        int m = mh * 32 + (reg & 3) + 8 * (reg >> 2) + 4 * h;
        int n = nt * 32 + l31;
        int o = m * 64 + n;
        ob[o] = accO[e][nt][reg] + bias[o];
      }
    }
  }
}

// ---------------------------------------------------------------------------
extern "C" void kernel_launch(void* const* d_in, const int* in_sizes, int n_in,
                              void* d_out, int out_size, void* d_ws, size_t ws_size,
                              hipStream_t stream) {
  (void)n_in; (void)out_size; (void)ws_size;
  const float* x    = (const float*)d_in[0];
  const float* P0   = (const float*)d_in[1];
  const float* P1   = (const float*)d_in[2];
  const float* P2   = (const float*)d_in[3];
  const float* P3   = (const float*)d_in[4];
  const float* bias = (const float*)d_in[5];
  float* out = (float*)d_out;

  // ws: Qbuf f32[128*256] (128 KB) | W1 bf16[65536] (128 KB) | W2 bf16[65536] (128 KB)
  float* Qbuf = (float*)d_ws;
  unsigned short* W1 = (unsigned short*)((char*)d_ws + 131072);
  unsigned short* W2 = (unsigned short*)((char*)d_ws + 262144);

  k_cayley<<<8, 256, 0, stream>>>(P1, P2, Qbuf);
  k_build<<<512, 256, 0, stream>>>(P0, P3, Qbuf, W1, W2);

  int batch = in_sizes[0] / 4096;
  k_main<<<batch / 4, 256, 0, stream>>>(x, W1, W2, bias, out);
}